// Round 17
// baseline (93.195 us; speedup 1.0000x reference)
//
#include <hip/hip_runtime.h>

#define D 128
#define PAD 48

typedef __attribute__((ext_vector_type(8))) short short8;
typedef __attribute__((ext_vector_type(4))) float f32x4;

// ---------- bf16 helpers (manual, RNE) ----------
static __device__ __forceinline__ unsigned short f2bf(float f) {
    unsigned int u = __float_as_uint(f);
    u += 0x7fffu + ((u >> 16) & 1u);
    return (unsigned short)(u >> 16);
}
static __device__ __forceinline__ float bf_lo(unsigned int v) {
    return __uint_as_float(v << 16);
}
static __device__ __forceinline__ float bf_hi(unsigned int v) {
    return __uint_as_float(v & 0xffff0000u);
}

// ---------- zero cnt[0..N] (cnt[N] = spill counter) + last-block W-prep ----------
__global__ __launch_bounds__(256) void zw_k(int* __restrict__ cnt,
                                            const float* __restrict__ W,
                                            unsigned short* __restrict__ Wtg,
                                            int N1) {
    int t = threadIdx.x;
    if (blockIdx.x == gridDim.x - 1) {  // W-prep: Wt[c][k]=bf16(W[k][c]), swizzled
        __shared__ unsigned short Wt[D * D];  // 32 KB
        const float4* Wv = (const float4*)W;
#pragma unroll
        for (int i = 0; i < 16; ++i) {
            int idx = i * 256 + t;       // 4096 float4 total
            int k = idx >> 5;            // W row
            int c0 = (idx & 31) * 4;     // W col
            float4 v = Wv[idx];
            float vv[4] = {v.x, v.y, v.z, v.w};
#pragma unroll
            for (int j = 0; j < 4; ++j) {
                int c = c0 + j;
                unsigned int B = (unsigned int)c * 256 + (unsigned int)k * 2;
                unsigned int sB = B ^ (((unsigned int)c & 7u) << 4);
                *(unsigned short*)((char*)Wt + sB) = f2bf(vv[j]);
            }
        }
        __syncthreads();
        const uint4* s4 = (const uint4*)Wt;
        uint4* g4 = (uint4*)Wtg;
#pragma unroll
        for (int i = 0; i < 8; ++i) g4[i * 256 + t] = s4[i * 256 + t];
    }
    int base = blockIdx.x * 1024 + t * 4;
#pragma unroll
    for (int j = 0; j < 4; ++j)
        if (base + j < N1) cnt[base + j] = 0;
}

// ---------- FUSED bin (count+fill, ONE atomic) + GEMM (2 tiles/block) ----------
// Every 3rd block (while available) bins 8 edges/thread: p=atomicAdd(cnt[d])
// is both degree count and slot in padded eidxp[d*PAD+p]; overflow -> spill
// list (deterministic fallback; ~never for Poisson(6.4)). Gemm blocks stage
// pre-swizzled Wtg->LDS once, then compute TWO 64-row tiles (amortized).
// h stored UNSCALED (dinv applied per-edge in agg). ost writes XOR-swizzled
// (byte ^= (row&7)<<4) to cut the 8-way b16 bank conflict to 4-way.
__global__ __launch_bounds__(256) void bg_k(const float* __restrict__ x,
                                            const unsigned short* __restrict__ Wtg,
                                            unsigned short* __restrict__ h,
                                            const int* __restrict__ ei,
                                            int* __restrict__ cnt,
                                            int* __restrict__ eidxp,
                                            int2* __restrict__ spill,
                                            int N, int E, int nbin, int ntiles) {
    __shared__ unsigned short Wt[D * D];       // 32 KB
    __shared__ unsigned short ost[4][16 * D];  // 16 KB
    int t = threadIdx.x;
    int bid = (int)blockIdx.x;

    bool isbin = (bid % 3 == 2) && (bid / 3 < nbin);
    if (isbin) {  // ---- bin path: 8 edges/thread, 8 independent chains ----
        int e = ((bid / 3) * 256 + t) * 8;
        if (e + 7 < E) {
            int4 sa = *(const int4*)&ei[e];
            int4 sb = *(const int4*)&ei[e + 4];
            int4 da = *(const int4*)&ei[E + e];
            int4 db = *(const int4*)&ei[E + e + 4];
            int dd[8] = {da.x, da.y, da.z, da.w, db.x, db.y, db.z, db.w};
            int ss[8] = {sa.x, sa.y, sa.z, sa.w, sb.x, sb.y, sb.z, sb.w};
#pragma unroll
            for (int j = 0; j < 8; ++j) {
                int p = atomicAdd(&cnt[dd[j]], 1);
                if (p < PAD) eidxp[dd[j] * PAD + p] = ss[j];
                else { int sp = atomicAdd(&cnt[N], 1); spill[sp] = make_int2(dd[j], ss[j]); }
            }
        } else {
            for (int q = e; q < E; ++q) {
                int s = ei[q], d = ei[E + q];
                int p = atomicAdd(&cnt[d], 1);
                if (p < PAD) eidxp[d * PAD + p] = s;
                else { int sp = atomicAdd(&cnt[N], 1); spill[sp] = make_int2(d, s); }
            }
        }
        return;
    }

    // ---- gemm path: 2 tiles per block, Wt staged once ----
    int tile2 = bid - (bid / 3 < nbin ? bid / 3 : nbin);
    int w = t >> 6, l = t & 63;
    int mrow = l & 15, kgrp = l >> 4;

    {   // linear coalesced 32 KB stage of pre-swizzled Wtg
        const uint4* g4 = (const uint4*)Wtg;
        uint4* s4 = (uint4*)Wt;
#pragma unroll
        for (int i2 = 0; i2 < 8; ++i2) s4[i2 * 256 + t] = g4[i2 * 256 + t];
    }
    __syncthreads();

#pragma unroll
    for (int rt = 0; rt < 2; ++rt) {
        int tile = tile2 * 2 + rt;
        if (tile >= ntiles) break;
        int row0 = tile * 64 + w * 16;  // N % 16 == 0
        if (row0 >= N) continue;

        short8 a[4];
#pragma unroll
        for (int kk = 0; kk < 4; ++kk) {
            const float* p = &x[(size_t)(row0 + mrow) * D + kk * 32 + kgrp * 8];
            float4 q0 = *(const float4*)p;
            float4 q1 = *(const float4*)(p + 4);
            short8 af;
            af[0] = (short)f2bf(q0.x); af[1] = (short)f2bf(q0.y);
            af[2] = (short)f2bf(q0.z); af[3] = (short)f2bf(q0.w);
            af[4] = (short)f2bf(q1.x); af[5] = (short)f2bf(q1.y);
            af[6] = (short)f2bf(q1.z); af[7] = (short)f2bf(q1.w);
            a[kk] = af;
        }

        f32x4 acc[8];
#pragma unroll
        for (int nt = 0; nt < 8; ++nt) {
            acc[nt] = (f32x4){0.f, 0.f, 0.f, 0.f};
#pragma unroll
            for (int kk = 0; kk < 4; ++kk) {
                unsigned int c = nt * 16 + mrow;
                unsigned int B = c * 256 + (unsigned int)(kk * 32 + kgrp * 8) * 2;
                unsigned int sB = B ^ ((c & 7u) << 4);
                short8 bf = *(const short8*)((const char*)Wt + sB);
                acc[nt] = __builtin_amdgcn_mfma_f32_16x16x32_bf16(a[kk], bf, acc[nt], 0, 0, 0);
            }
        }
        // UNSCALED h via ost, XOR-swizzled writes (row&7)<<4
#pragma unroll
        for (int nt = 0; nt < 8; ++nt)
#pragma unroll
            for (int j = 0; j < 4; ++j) {
                unsigned int rr = kgrp * 4 + j;
                unsigned int B = rr * 256 + nt * 32 + mrow * 2;
                unsigned int sB = B ^ ((rr & 7u) << 4);
                *(unsigned short*)((char*)ost[w] + sB) = f2bf(acc[nt][j]);
            }
        {   // same-wave LDS write->read (program order; ost[w] wave-private)
            const uint4* os4 = (const uint4*)ost[w];
            uint4* H4 = (uint4*)h;
#pragma unroll
            for (int i2 = 0; i2 < 4; ++i2) {
                int r2 = i2 * 4 + (l >> 4);   // row 0..15
                int c = l & 15;               // uint4 chunk
                uint4 v = os4[r2 * 16 + (c ^ (r2 & 7))];  // undo XOR swizzle
                H4[(size_t)row0 * 16 + r2 * 16 + c] = v;
            }
        }
    }
}

// ---------- pull aggregate from PADDED table + per-edge dinv + epilogue ----------
// FOUR nodes per wave (16-lane group per node); lane col owns 8 cols (uint4).
// Per edge: broadcast eidxp + cnt[s] loads, rsqrt, gather, 8 fma. No
// cross-lane ops -> group divergence safe. Residual from f32 x (NT loads).
__global__ __launch_bounds__(256) void agg_k(const unsigned int* __restrict__ h2,
                                             const float* __restrict__ x,
                                             const float* __restrict__ b,
                                             const int* __restrict__ cnt,
                                             const int* __restrict__ eidxp,
                                             const int2* __restrict__ spill,
                                             float* __restrict__ out, int N) {
    int w = threadIdx.x >> 6;
    int lane = threadIdx.x & 63;
    int g = lane >> 4;
    int col = lane & 15;
    int i0 = (blockIdx.x * 4 + w) * 4 + g;
    bool valid = i0 < N;
    int i = valid ? i0 : N - 1;   // clamp; clamped groups compute but don't store

    int deg = cnt[i];                       // uniform within group
    float di = rsqrtf((float)deg + 1.0f);
    int ib = i * PAD;

    const uint4* H16 = (const uint4*)h2;

    float a0, a1, a2, a3, a4, a5, a6, a7;
    {   // self-loop: h[i] * di (outer di applied at end -> di^2 total)
        uint4 sv = H16[(size_t)i * 16 + col];
        a0 = bf_lo(sv.x) * di; a1 = bf_hi(sv.x) * di;
        a2 = bf_lo(sv.y) * di; a3 = bf_hi(sv.y) * di;
        a4 = bf_lo(sv.z) * di; a5 = bf_hi(sv.z) * di;
        a6 = bf_lo(sv.w) * di; a7 = bf_hi(sv.w) * di;
    }

    int dk = deg < PAD ? deg : PAD;
    int k = 0;
    for (; k + 4 <= dk; k += 4) {  // 4 independent gather chains in flight
        int s0 = eidxp[ib + k];
        int s1 = eidxp[ib + k + 1];
        int s2 = eidxp[ib + k + 2];
        int s3 = eidxp[ib + k + 3];
        float e0 = rsqrtf((float)cnt[s0] + 1.0f);
        float e1 = rsqrtf((float)cnt[s1] + 1.0f);
        float e2 = rsqrtf((float)cnt[s2] + 1.0f);
        float e3 = rsqrtf((float)cnt[s3] + 1.0f);
        uint4 v0 = H16[(size_t)s0 * 16 + col];
        uint4 v1 = H16[(size_t)s1 * 16 + col];
        uint4 v2 = H16[(size_t)s2 * 16 + col];
        uint4 v3 = H16[(size_t)s3 * 16 + col];
        a0 = fmaf(bf_lo(v0.x), e0, a0); a1 = fmaf(bf_hi(v0.x), e0, a1);
        a2 = fmaf(bf_lo(v0.y), e0, a2); a3 = fmaf(bf_hi(v0.y), e0, a3);
        a4 = fmaf(bf_lo(v0.z), e0, a4); a5 = fmaf(bf_hi(v0.z), e0, a5);
        a6 = fmaf(bf_lo(v0.w), e0, a6); a7 = fmaf(bf_hi(v0.w), e0, a7);
        a0 = fmaf(bf_lo(v1.x), e1, a0); a1 = fmaf(bf_hi(v1.x), e1, a1);
        a2 = fmaf(bf_lo(v1.y), e1, a2); a3 = fmaf(bf_hi(v1.y), e1, a3);
        a4 = fmaf(bf_lo(v1.z), e1, a4); a5 = fmaf(bf_hi(v1.z), e1, a5);
        a6 = fmaf(bf_lo(v1.w), e1, a6); a7 = fmaf(bf_hi(v1.w), e1, a7);
        a0 = fmaf(bf_lo(v2.x), e2, a0); a1 = fmaf(bf_hi(v2.x), e2, a1);
        a2 = fmaf(bf_lo(v2.y), e2, a2); a3 = fmaf(bf_hi(v2.y), e2, a3);
        a4 = fmaf(bf_lo(v2.z), e2, a4); a5 = fmaf(bf_hi(v2.z), e2, a5);
        a6 = fmaf(bf_lo(v2.w), e2, a6); a7 = fmaf(bf_hi(v2.w), e2, a7);
        a0 = fmaf(bf_lo(v3.x), e3, a0); a1 = fmaf(bf_hi(v3.x), e3, a1);
        a2 = fmaf(bf_lo(v3.y), e3, a2); a3 = fmaf(bf_hi(v3.y), e3, a3);
        a4 = fmaf(bf_lo(v3.z), e3, a4); a5 = fmaf(bf_hi(v3.z), e3, a5);
        a6 = fmaf(bf_lo(v3.w), e3, a6); a7 = fmaf(bf_hi(v3.w), e3, a7);
    }
    for (; k < dk; ++k) {
        int s = eidxp[ib + k];
        float e0 = rsqrtf((float)cnt[s] + 1.0f);
        uint4 v = H16[(size_t)s * 16 + col];
        a0 = fmaf(bf_lo(v.x), e0, a0); a1 = fmaf(bf_hi(v.x), e0, a1);
        a2 = fmaf(bf_lo(v.y), e0, a2); a3 = fmaf(bf_hi(v.y), e0, a3);
        a4 = fmaf(bf_lo(v.z), e0, a4); a5 = fmaf(bf_hi(v.z), e0, a5);
        a6 = fmaf(bf_lo(v.w), e0, a6); a7 = fmaf(bf_hi(v.w), e0, a7);
    }
    if (deg > PAD) {  // spill scan (practically never; correctness fallback)
        int sc = cnt[N];
        for (int j = 0; j < sc; ++j) {
            int2 pr = spill[j];
            if (pr.x == i) {
                int s = pr.y;
                float e0 = rsqrtf((float)cnt[s] + 1.0f);
                uint4 v = H16[(size_t)s * 16 + col];
                a0 = fmaf(bf_lo(v.x), e0, a0); a1 = fmaf(bf_hi(v.x), e0, a1);
                a2 = fmaf(bf_lo(v.y), e0, a2); a3 = fmaf(bf_hi(v.y), e0, a3);
                a4 = fmaf(bf_lo(v.z), e0, a4); a5 = fmaf(bf_hi(v.z), e0, a5);
                a6 = fmaf(bf_lo(v.w), e0, a6); a7 = fmaf(bf_hi(v.w), e0, a7);
            }
        }
    }

    if (valid) {  // all 64 lanes store: 4 rows per wave, 32B per lane
        size_t ob = (size_t)i * D + col * 8;
        float4 b0 = *(const float4*)&b[col * 8];
        float4 b1 = *(const float4*)&b[col * 8 + 4];
        const f32x4* px0 = (const f32x4*)&x[ob];
        const f32x4* px1 = (const f32x4*)&x[ob + 4];
        f32x4 x0 = __builtin_nontemporal_load(px0);
        f32x4 x1 = __builtin_nontemporal_load(px1);
        f32x4 o0, o1;
        o0.x = x0.x + fmaxf(a0 * di + b0.x, 0.f);
        o0.y = x0.y + fmaxf(a1 * di + b0.y, 0.f);
        o0.z = x0.z + fmaxf(a2 * di + b0.z, 0.f);
        o0.w = x0.w + fmaxf(a3 * di + b0.w, 0.f);
        o1.x = x1.x + fmaxf(a4 * di + b1.x, 0.f);
        o1.y = x1.y + fmaxf(a5 * di + b1.y, 0.f);
        o1.z = x1.z + fmaxf(a6 * di + b1.z, 0.f);
        o1.w = x1.w + fmaxf(a7 * di + b1.w, 0.f);
        __builtin_nontemporal_store(o0, (f32x4*)&out[ob]);
        __builtin_nontemporal_store(o1, (f32x4*)&out[ob + 4]);
    }
}

extern "C" void kernel_launch(void* const* d_in, const int* in_sizes, int n_in,
                              void* d_out, int out_size, void* d_ws, size_t ws_size,
                              hipStream_t stream) {
    const float* x = (const float*)d_in[0];
    const int* ei = (const int*)d_in[1];
    const float* W = (const float*)d_in[2];
    const float* b = (const float*)d_in[3];
    float* out = (float*)d_out;

    int N = in_sizes[0] / D;
    int E = in_sizes[1] / 2;

    char* ws = (char*)d_ws;
    int* cnt            = (int*)(ws + 0);                        // (N+1)*4; cnt[N]=spillcnt
    unsigned short* Wtg = (unsigned short*)(ws + (512 << 10));   // 32 KB
    int2* spill         = (int2*)(ws + (1024 << 10));            // E*8 = 5.12 MB cap
    int* eidxp          = (int*)(ws + (8192 << 10));             // N*PAD*4 = 19.2 MB
    unsigned short* h   = (unsigned short*)(ws + (28672 << 10)); // N*128*2 = 25.6 MB
    unsigned int* h2    = (unsigned int*)h;

    int N1 = N + 1;
    int nzero = (N1 + 1023) / 1024;
    zw_k<<<nzero, 256, 0, stream>>>(cnt, W, Wtg, N1);

    int ntiles = (N + 63) / 64;
    int ngt = (ntiles + 1) / 2;       // 2 tiles per gemm block
    int nbin = (E / 8 + 255) / 256;   // 8 edges/thread
    bg_k<<<nbin + ngt, 256, 0, stream>>>(x, Wtg, h, ei, cnt, eidxp, spill,
                                         N, E, nbin, ntiles);
    agg_k<<<(N + 15) / 16, 256, 0, stream>>>(h2, x, b, cnt, eidxp, spill, out, N);
}

// Round 18
// 88.873 us; speedup vs baseline: 1.0486x; 1.0486x over previous
//
#include <hip/hip_runtime.h>

#define D 128
#define PAD 48

typedef __attribute__((ext_vector_type(8))) short short8;
typedef __attribute__((ext_vector_type(4))) float f32x4;

// ---------- bf16 helpers (manual, RNE) ----------
static __device__ __forceinline__ unsigned short f2bf(float f) {
    unsigned int u = __float_as_uint(f);
    u += 0x7fffu + ((u >> 16) & 1u);
    return (unsigned short)(u >> 16);
}
static __device__ __forceinline__ float bf_lo(unsigned int v) {
    return __uint_as_float(v << 16);
}
static __device__ __forceinline__ float bf_hi(unsigned int v) {
    return __uint_as_float(v & 0xffff0000u);
}

// ---------- zero cnt[0..N] (cnt[N] = spill counter) + last-block W-prep ----------
__global__ __launch_bounds__(256) void zw_k(int* __restrict__ cnt,
                                            const float* __restrict__ W,
                                            unsigned short* __restrict__ Wtg,
                                            int N1) {
    int t = threadIdx.x;
    if (blockIdx.x == gridDim.x - 1) {  // W-prep: Wt[c][k]=bf16(W[k][c]), swizzled
        __shared__ unsigned short Wt[D * D];  // 32 KB
        const float4* Wv = (const float4*)W;
#pragma unroll
        for (int i = 0; i < 16; ++i) {
            int idx = i * 256 + t;       // 4096 float4 total
            int k = idx >> 5;            // W row
            int c0 = (idx & 31) * 4;     // W col
            float4 v = Wv[idx];
            float vv[4] = {v.x, v.y, v.z, v.w};
#pragma unroll
            for (int j = 0; j < 4; ++j) {
                int c = c0 + j;
                unsigned int B = (unsigned int)c * 256 + (unsigned int)k * 2;
                unsigned int sB = B ^ (((unsigned int)c & 7u) << 4);
                *(unsigned short*)((char*)Wt + sB) = f2bf(vv[j]);
            }
        }
        __syncthreads();
        const uint4* s4 = (const uint4*)Wt;
        uint4* g4 = (uint4*)Wtg;
#pragma unroll
        for (int i = 0; i < 8; ++i) g4[i * 256 + t] = s4[i * 256 + t];
    }
    int base = blockIdx.x * 1024 + t * 4;
#pragma unroll
    for (int j = 0; j < 4; ++j)
        if (base + j < N1) cnt[base + j] = 0;
}

// ---------- FUSED bin (count+fill, ONE atomic) + GEMM (1 tile/block) ----------
// Round-16 geometry restored (2188 blocks: latency-hiding needs the bigger
// grid — round 17's 1095-block variant regressed). Every 3rd block (while
// available) bins 4 edges/thread: p=atomicAdd(cnt[d]) is both degree count
// and slot in padded eidxp[d*PAD+p]; overflow -> spill list. Gemm blocks
// stage pre-swizzled Wtg->LDS linearly, ONE 64-row tile each. h stored
// UNSCALED (dinv applied per-edge in agg). ost writes XOR-swizzled.
__global__ __launch_bounds__(256) void bg_k(const float* __restrict__ x,
                                            const unsigned short* __restrict__ Wtg,
                                            unsigned short* __restrict__ h,
                                            const int* __restrict__ ei,
                                            int* __restrict__ cnt,
                                            int* __restrict__ eidxp,
                                            int2* __restrict__ spill,
                                            int N, int E, int nbin) {
    __shared__ unsigned short Wt[D * D];       // 32 KB
    __shared__ unsigned short ost[4][16 * D];  // 16 KB
    int t = threadIdx.x;
    int bid = (int)blockIdx.x;

    bool isbin = (bid % 3 == 2) && (bid / 3 < nbin);
    if (isbin) {  // ---- bin path: 4 edges/thread ----
        int e = ((bid / 3) * 256 + t) * 4;
        if (e + 3 < E) {
            int4 s = *(const int4*)&ei[e];
            int4 d = *(const int4*)&ei[E + e];
            int p0 = atomicAdd(&cnt[d.x], 1);
            if (p0 < PAD) eidxp[d.x * PAD + p0] = s.x;
            else { int sp = atomicAdd(&cnt[N], 1); spill[sp] = make_int2(d.x, s.x); }
            int p1 = atomicAdd(&cnt[d.y], 1);
            if (p1 < PAD) eidxp[d.y * PAD + p1] = s.y;
            else { int sp = atomicAdd(&cnt[N], 1); spill[sp] = make_int2(d.y, s.y); }
            int p2 = atomicAdd(&cnt[d.z], 1);
            if (p2 < PAD) eidxp[d.z * PAD + p2] = s.z;
            else { int sp = atomicAdd(&cnt[N], 1); spill[sp] = make_int2(d.z, s.z); }
            int p3 = atomicAdd(&cnt[d.w], 1);
            if (p3 < PAD) eidxp[d.w * PAD + p3] = s.w;
            else { int sp = atomicAdd(&cnt[N], 1); spill[sp] = make_int2(d.w, s.w); }
        } else {
            for (int q = e; q < E; ++q) {
                int s = ei[q], d = ei[E + q];
                int p = atomicAdd(&cnt[d], 1);
                if (p < PAD) eidxp[d * PAD + p] = s;
                else { int sp = atomicAdd(&cnt[N], 1); spill[sp] = make_int2(d, s); }
            }
        }
        return;
    }

    // ---- gemm path: 1 tile per block ----
    int tile = bid - (bid / 3 < nbin ? bid / 3 : nbin);
    int w = t >> 6, l = t & 63;
    int mrow = l & 15, kgrp = l >> 4;
    int row0 = tile * 64 + w * 16;  // N % 16 == 0

    {   // linear coalesced 32 KB stage of pre-swizzled Wtg
        const uint4* g4 = (const uint4*)Wtg;
        uint4* s4 = (uint4*)Wt;
#pragma unroll
        for (int i2 = 0; i2 < 8; ++i2) s4[i2 * 256 + t] = g4[i2 * 256 + t];
    }
    __syncthreads();
    if (row0 >= N) return;

    short8 a[4];
#pragma unroll
    for (int kk = 0; kk < 4; ++kk) {
        const float* p = &x[(size_t)(row0 + mrow) * D + kk * 32 + kgrp * 8];
        float4 q0 = *(const float4*)p;
        float4 q1 = *(const float4*)(p + 4);
        short8 af;
        af[0] = (short)f2bf(q0.x); af[1] = (short)f2bf(q0.y);
        af[2] = (short)f2bf(q0.z); af[3] = (short)f2bf(q0.w);
        af[4] = (short)f2bf(q1.x); af[5] = (short)f2bf(q1.y);
        af[6] = (short)f2bf(q1.z); af[7] = (short)f2bf(q1.w);
        a[kk] = af;
    }

    f32x4 acc[8];
#pragma unroll
    for (int nt = 0; nt < 8; ++nt) {
        acc[nt] = (f32x4){0.f, 0.f, 0.f, 0.f};
#pragma unroll
        for (int kk = 0; kk < 4; ++kk) {
            unsigned int c = nt * 16 + mrow;
            unsigned int B = c * 256 + (unsigned int)(kk * 32 + kgrp * 8) * 2;
            unsigned int sB = B ^ ((c & 7u) << 4);
            short8 bf = *(const short8*)((const char*)Wt + sB);
            acc[nt] = __builtin_amdgcn_mfma_f32_16x16x32_bf16(a[kk], bf, acc[nt], 0, 0, 0);
        }
    }
    // UNSCALED h via ost, XOR-swizzled writes (row&7)<<4
#pragma unroll
    for (int nt = 0; nt < 8; ++nt)
#pragma unroll
        for (int j = 0; j < 4; ++j) {
            unsigned int rr = kgrp * 4 + j;
            unsigned int B = rr * 256 + nt * 32 + mrow * 2;
            unsigned int sB = B ^ ((rr & 7u) << 4);
            *(unsigned short*)((char*)ost[w] + sB) = f2bf(acc[nt][j]);
        }
    {   // same-wave LDS write->read (program order; ost[w] wave-private)
        const uint4* os4 = (const uint4*)ost[w];
        uint4* H4 = (uint4*)h;
#pragma unroll
        for (int i2 = 0; i2 < 4; ++i2) {
            int r2 = i2 * 4 + (l >> 4);   // row 0..15
            int c = l & 15;               // uint4 chunk
            uint4 v = os4[r2 * 16 + (c ^ (r2 & 7))];  // undo XOR swizzle
            H4[(size_t)row0 * 16 + r2 * 16 + c] = v;
        }
    }
}

// ---------- pull aggregate from PADDED table + per-edge dinv + epilogue ----------
// FOUR nodes per wave (16-lane group per node); lane col owns 8 cols (uint4).
// Per edge: broadcast eidxp + cnt[s] loads, rsqrt, gather, 8 fma. No
// cross-lane ops -> group divergence safe. Residual from f32 x (NT loads).
__global__ __launch_bounds__(256) void agg_k(const unsigned int* __restrict__ h2,
                                             const float* __restrict__ x,
                                             const float* __restrict__ b,
                                             const int* __restrict__ cnt,
                                             const int* __restrict__ eidxp,
                                             const int2* __restrict__ spill,
                                             float* __restrict__ out, int N) {
    int w = threadIdx.x >> 6;
    int lane = threadIdx.x & 63;
    int g = lane >> 4;
    int col = lane & 15;
    int i0 = (blockIdx.x * 4 + w) * 4 + g;
    bool valid = i0 < N;
    int i = valid ? i0 : N - 1;   // clamp; clamped groups compute but don't store

    int deg = cnt[i];                       // uniform within group
    float di = rsqrtf((float)deg + 1.0f);
    int ib = i * PAD;

    const uint4* H16 = (const uint4*)h2;

    float a0, a1, a2, a3, a4, a5, a6, a7;
    {   // self-loop: h[i] * di (outer di applied at end -> di^2 total)
        uint4 sv = H16[(size_t)i * 16 + col];
        a0 = bf_lo(sv.x) * di; a1 = bf_hi(sv.x) * di;
        a2 = bf_lo(sv.y) * di; a3 = bf_hi(sv.y) * di;
        a4 = bf_lo(sv.z) * di; a5 = bf_hi(sv.z) * di;
        a6 = bf_lo(sv.w) * di; a7 = bf_hi(sv.w) * di;
    }

    int dk = deg < PAD ? deg : PAD;
    int k = 0;
    for (; k + 4 <= dk; k += 4) {  // 4 independent gather chains in flight
        int s0 = eidxp[ib + k];
        int s1 = eidxp[ib + k + 1];
        int s2 = eidxp[ib + k + 2];
        int s3 = eidxp[ib + k + 3];
        float e0 = rsqrtf((float)cnt[s0] + 1.0f);
        float e1 = rsqrtf((float)cnt[s1] + 1.0f);
        float e2 = rsqrtf((float)cnt[s2] + 1.0f);
        float e3 = rsqrtf((float)cnt[s3] + 1.0f);
        uint4 v0 = H16[(size_t)s0 * 16 + col];
        uint4 v1 = H16[(size_t)s1 * 16 + col];
        uint4 v2 = H16[(size_t)s2 * 16 + col];
        uint4 v3 = H16[(size_t)s3 * 16 + col];
        a0 = fmaf(bf_lo(v0.x), e0, a0); a1 = fmaf(bf_hi(v0.x), e0, a1);
        a2 = fmaf(bf_lo(v0.y), e0, a2); a3 = fmaf(bf_hi(v0.y), e0, a3);
        a4 = fmaf(bf_lo(v0.z), e0, a4); a5 = fmaf(bf_hi(v0.z), e0, a5);
        a6 = fmaf(bf_lo(v0.w), e0, a6); a7 = fmaf(bf_hi(v0.w), e0, a7);
        a0 = fmaf(bf_lo(v1.x), e1, a0); a1 = fmaf(bf_hi(v1.x), e1, a1);
        a2 = fmaf(bf_lo(v1.y), e1, a2); a3 = fmaf(bf_hi(v1.y), e1, a3);
        a4 = fmaf(bf_lo(v1.z), e1, a4); a5 = fmaf(bf_hi(v1.z), e1, a5);
        a6 = fmaf(bf_lo(v1.w), e1, a6); a7 = fmaf(bf_hi(v1.w), e1, a7);
        a0 = fmaf(bf_lo(v2.x), e2, a0); a1 = fmaf(bf_hi(v2.x), e2, a1);
        a2 = fmaf(bf_lo(v2.y), e2, a2); a3 = fmaf(bf_hi(v2.y), e2, a3);
        a4 = fmaf(bf_lo(v2.z), e2, a4); a5 = fmaf(bf_hi(v2.z), e2, a5);
        a6 = fmaf(bf_lo(v2.w), e2, a6); a7 = fmaf(bf_hi(v2.w), e2, a7);
        a0 = fmaf(bf_lo(v3.x), e3, a0); a1 = fmaf(bf_hi(v3.x), e3, a1);
        a2 = fmaf(bf_lo(v3.y), e3, a2); a3 = fmaf(bf_hi(v3.y), e3, a3);
        a4 = fmaf(bf_lo(v3.z), e3, a4); a5 = fmaf(bf_hi(v3.z), e3, a5);
        a6 = fmaf(bf_lo(v3.w), e3, a6); a7 = fmaf(bf_hi(v3.w), e3, a7);
    }
    for (; k < dk; ++k) {
        int s = eidxp[ib + k];
        float e0 = rsqrtf((float)cnt[s] + 1.0f);
        uint4 v = H16[(size_t)s * 16 + col];
        a0 = fmaf(bf_lo(v.x), e0, a0); a1 = fmaf(bf_hi(v.x), e0, a1);
        a2 = fmaf(bf_lo(v.y), e0, a2); a3 = fmaf(bf_hi(v.y), e0, a3);
        a4 = fmaf(bf_lo(v.z), e0, a4); a5 = fmaf(bf_hi(v.z), e0, a5);
        a6 = fmaf(bf_lo(v.w), e0, a6); a7 = fmaf(bf_hi(v.w), e0, a7);
    }
    if (deg > PAD) {  // spill scan (practically never; correctness fallback)
        int sc = cnt[N];
        for (int j = 0; j < sc; ++j) {
            int2 pr = spill[j];
            if (pr.x == i) {
                int s = pr.y;
                float e0 = rsqrtf((float)cnt[s] + 1.0f);
                uint4 v = H16[(size_t)s * 16 + col];
                a0 = fmaf(bf_lo(v.x), e0, a0); a1 = fmaf(bf_hi(v.x), e0, a1);
                a2 = fmaf(bf_lo(v.y), e0, a2); a3 = fmaf(bf_hi(v.y), e0, a3);
                a4 = fmaf(bf_lo(v.z), e0, a4); a5 = fmaf(bf_hi(v.z), e0, a5);
                a6 = fmaf(bf_lo(v.w), e0, a6); a7 = fmaf(bf_hi(v.w), e0, a7);
            }
        }
    }

    if (valid) {  // all 64 lanes store: 4 rows per wave, 32B per lane
        size_t ob = (size_t)i * D + col * 8;
        float4 b0 = *(const float4*)&b[col * 8];
        float4 b1 = *(const float4*)&b[col * 8 + 4];
        const f32x4* px0 = (const f32x4*)&x[ob];
        const f32x4* px1 = (const f32x4*)&x[ob + 4];
        f32x4 x0 = __builtin_nontemporal_load(px0);
        f32x4 x1 = __builtin_nontemporal_load(px1);
        f32x4 o0, o1;
        o0.x = x0.x + fmaxf(a0 * di + b0.x, 0.f);
        o0.y = x0.y + fmaxf(a1 * di + b0.y, 0.f);
        o0.z = x0.z + fmaxf(a2 * di + b0.z, 0.f);
        o0.w = x0.w + fmaxf(a3 * di + b0.w, 0.f);
        o1.x = x1.x + fmaxf(a4 * di + b1.x, 0.f);
        o1.y = x1.y + fmaxf(a5 * di + b1.y, 0.f);
        o1.z = x1.z + fmaxf(a6 * di + b1.z, 0.f);
        o1.w = x1.w + fmaxf(a7 * di + b1.w, 0.f);
        __builtin_nontemporal_store(o0, (f32x4*)&out[ob]);
        __builtin_nontemporal_store(o1, (f32x4*)&out[ob + 4]);
    }
}

extern "C" void kernel_launch(void* const* d_in, const int* in_sizes, int n_in,
                              void* d_out, int out_size, void* d_ws, size_t ws_size,
                              hipStream_t stream) {
    const float* x = (const float*)d_in[0];
    const int* ei = (const int*)d_in[1];
    const float* W = (const float*)d_in[2];
    const float* b = (const float*)d_in[3];
    float* out = (float*)d_out;

    int N = in_sizes[0] / D;
    int E = in_sizes[1] / 2;

    char* ws = (char*)d_ws;
    int* cnt            = (int*)(ws + 0);                        // (N+1)*4; cnt[N]=spillcnt
    unsigned short* Wtg = (unsigned short*)(ws + (512 << 10));   // 32 KB
    int2* spill         = (int2*)(ws + (1024 << 10));            // E*8 = 5.12 MB cap
    int* eidxp          = (int*)(ws + (8192 << 10));             // N*PAD*4 = 19.2 MB
    unsigned short* h   = (unsigned short*)(ws + (28672 << 10)); // N*128*2 = 25.6 MB
    unsigned int* h2    = (unsigned int*)h;

    int N1 = N + 1;
    int nzero = (N1 + 1023) / 1024;
    zw_k<<<nzero, 256, 0, stream>>>(cnt, W, Wtg, N1);

    int ntiles = (N + 63) / 64;
    int nbin = (E / 4 + 255) / 256;   // 4 edges/thread (round-16 geometry)
    bg_k<<<nbin + ntiles, 256, 0, stream>>>(x, Wtg, h, ei, cnt, eidxp, spill,
                                            N, E, nbin);
    agg_k<<<(N + 15) / 16, 256, 0, stream>>>(h2, x, b, cnt, eidxp, spill, out, N);
}